// Round 5
// baseline (780.340 us; speedup 1.0000x reference)
//
#include <hip/hip_runtime.h>
#include <hip/hip_cooperative_groups.h>

namespace cg = cooperative_groups;

// Problem dims (fixed)
#define BB   4
#define LQ   1024
#define LK   2048
#define D1   1024
#define D2   1280

typedef unsigned short u16;
typedef __attribute__((ext_vector_type(8))) short   short8;   // 8 bf16 = 4 VGPRs
typedef __attribute__((ext_vector_type(4))) float   floatx4;  // MFMA accum

__device__ __forceinline__ u16 f2bf(float f) {
    unsigned u = __float_as_uint(f);
    unsigned r = (u + 0x7FFFu + ((u >> 16) & 1u)) >> 16;   // RNE
    return (u16)r;
}

// async global->LDS, 16B per lane; LDS dest = wave-uniform base + lane*16
__device__ __forceinline__ void gl_lds16(const void* g, void* l) {
    __builtin_amdgcn_global_load_lds(
        (const __attribute__((address_space(1))) unsigned int*)g,
        (__attribute__((address_space(3))) unsigned int*)l, 16, 0, 0);
}

struct CastDesc {
    const float* src[6];
    u16*         dst[6];
    long         end[6];      // cumulative end in QUADS (4 elems)
};

enum { EPI_F32_BIAS, EPI_KV, EPI_EXP, EPI_ROWSCALE };

// ---------------------------------------------------------------------------
// gemm_stage: body of the measured-best 2-phase GEMM (m97-style), with block
// ids passed in (caller decodes) and LDS passed in (shared across stages).
// ---------------------------------------------------------------------------
template <int BM, int BN, int EPI>
__device__ __forceinline__ void gemm_stage(
    int bx, int by, int bz,
    const u16* __restrict__ A, const u16* __restrict__ B,
    void* __restrict__ C, const float* __restrict__ bias,
    int Kd, int lda, int ldb, int ldc,
    long sA, long sB, long sC, float scale,
    const u16* __restrict__ A2, const u16* __restrict__ B2,
    void* __restrict__ C2, const float* __restrict__ bias2,
    int ldc2, long sC2, float* __restrict__ rsum,
    u16* As, u16* Bs)
{
    constexpr bool TALL = (BM == 256);
    constexpr int  NJ   = TALL ? (BN / 16) : (BN / 32);  // j-frags per wave
    constexpr int  AISS = BM / 32;    // A staging issues per thread
    constexpr int  NBI  = BN / 32;    // B staging issues per thread

    const bool isV = (EPI == EPI_KV) && (bz >= BB);
    const int  b   = isV ? bz - BB : bz;

    const u16* Ab = (isV ? A2 : A) + (long)b * sA + (long)by * BM * lda;
    const u16* Bb = (isV ? B2 : B) + (long)b * sB + (long)bx * BN * ldb;

    const int t    = threadIdx.x;
    const int w    = t >> 6;              // wave 0..3
    const int l    = t & 63;
    const int l16  = l & 15;
    const int quad = l >> 4;
    const int wm   = TALL ? w * 64 : (w >> 1) * 64;
    const int wn   = TALL ? 0      : (w & 1) * (BN / 2);

    floatx4 acc[4][NJ];
    #pragma unroll
    for (int i = 0; i < 4; ++i)
        #pragma unroll
        for (int j = 0; j < NJ; ++j)
            acc[i][j] = (floatx4){0.f, 0.f, 0.f, 0.f};

    for (int k0 = 0; k0 < Kd; k0 += 64) {
        #pragma unroll
        for (int c = 0; c < AISS; ++c) {
            const int idx = (w * AISS + c) * 64 + l;
            const int mr  = idx >> 3;
            const int kq  = (idx & 7) ^ (mr & 7);
            gl_lds16(Ab + (long)mr * lda + k0 + kq * 8, (char*)As + (w * AISS + c) * 1024);
        }
        #pragma unroll
        for (int c = 0; c < NBI; ++c) {
            const int idx = (w * NBI + c) * 64 + l;
            const int mr  = idx >> 3;
            const int kq  = (idx & 7) ^ (mr & 7);
            gl_lds16(Bb + (long)mr * ldb + k0 + kq * 8, (char*)Bs + (w * NBI + c) * 1024);
        }
        __syncthreads();

        #pragma unroll
        for (int q = 0; q < 2; ++q) {
            const int sc = ((q * 4 + quad) ^ (l & 7)) * 8;
            short8 af[4], bfr[NJ];
            #pragma unroll
            for (int i = 0; i < 4; ++i)
                af[i]  = *(const short8*)(As + (wm + i * 16 + l16) * 64 + sc);
            #pragma unroll
            for (int j = 0; j < NJ; ++j)
                bfr[j] = *(const short8*)(Bs + (wn + j * 16 + l16) * 64 + sc);
            #pragma unroll
            for (int i = 0; i < 4; ++i)
                #pragma unroll
                for (int j = 0; j < NJ; ++j)
                    acc[i][j] = __builtin_amdgcn_mfma_f32_16x16x32_bf16(
                        af[i], bfr[j], acc[i][j], 0, 0, 0);
        }
        __syncthreads();
    }

    const int mb = by * BM + wm;
    const int nb = bx * BN + wn;

    if (EPI == EPI_F32_BIAS) {
        float* Cp = (float*)C + (long)bz * sC;
        #pragma unroll
        for (int i = 0; i < 4; ++i)
            #pragma unroll
            for (int j = 0; j < NJ; ++j) {
                const int col  = nb + j * 16 + l16;
                const int row0 = mb + i * 16 + quad * 4;
                const float bs = bias[col];
                #pragma unroll
                for (int r = 0; r < 4; ++r)
                    Cp[(long)(row0 + r) * ldc + col] = acc[i][j][r] + bs;
            }
    } else if (EPI == EPI_KV) {
        if (!isV) {
            u16* Cp = (u16*)C + (long)b * sC;
            #pragma unroll
            for (int i = 0; i < 4; ++i)
                #pragma unroll
                for (int j = 0; j < NJ; ++j) {
                    const int col  = nb + j * 16 + l16;
                    const int row0 = mb + i * 16 + quad * 4;
                    const float bs = bias[col];
                    #pragma unroll
                    for (int r = 0; r < 4; ++r)
                        Cp[(long)(row0 + r) * ldc + col] = f2bf(acc[i][j][r] + bs);
                }
        } else {
            u16* Cp = (u16*)C2 + (long)b * sC2;
            #pragma unroll
            for (int i = 0; i < 4; ++i)
                #pragma unroll
                for (int j = 0; j < NJ; ++j) {
                    const int col  = nb + j * 16 + l16;
                    const int row0 = mb + i * 16 + quad * 4;
                    const float bs = bias2[col];
                    const floatx4 vv = acc[i][j];
                    ushort4 pk;
                    pk.x = f2bf(vv[0] + bs); pk.y = f2bf(vv[1] + bs);
                    pk.z = f2bf(vv[2] + bs); pk.w = f2bf(vv[3] + bs);
                    *(ushort4*)(Cp + (long)col * ldc2 + row0) = pk;
                }
        }
    } else if (EPI == EPI_EXP) {
        u16* Cp = (u16*)C + (long)bz * sC;
        float lsum[4][4];
        #pragma unroll
        for (int i = 0; i < 4; ++i)
            #pragma unroll
            for (int r = 0; r < 4; ++r)
                lsum[i][r] = 0.f;
        #pragma unroll
        for (int i = 0; i < 4; ++i)
            #pragma unroll
            for (int j = 0; j < NJ; ++j) {
                const int col  = nb + j * 16 + l16;
                const int row0 = mb + i * 16 + quad * 4;
                #pragma unroll
                for (int r = 0; r < 4; ++r) {
                    const float e = __expf(acc[i][j][r] * scale);
                    Cp[(long)(row0 + r) * ldc + col] = f2bf(e);
                    lsum[i][r] += e;
                }
            }
        float* rp = rsum + (long)bz * LQ;
        #pragma unroll
        for (int i = 0; i < 4; ++i)
            #pragma unroll
            for (int r = 0; r < 4; ++r) {
                float s = lsum[i][r];
                s += __shfl_xor(s, 1);
                s += __shfl_xor(s, 2);
                s += __shfl_xor(s, 4);
                s += __shfl_xor(s, 8);
                if (l16 == 0)
                    atomicAdd(rp + mb + i * 16 + quad * 4 + r, s);
            }
    } else { // EPI_ROWSCALE
        u16* Cp = (u16*)C + (long)bz * sC;
        const float* rp = rsum + (long)bz * LQ;
        #pragma unroll
        for (int i = 0; i < 4; ++i) {
            const int row0 = mb + i * 16 + quad * 4;
            float inv[4];
            #pragma unroll
            for (int r = 0; r < 4; ++r)
                inv[r] = 1.0f / rp[row0 + r];
            #pragma unroll
            for (int j = 0; j < NJ; ++j) {
                const int col = nb + j * 16 + l16;
                #pragma unroll
                for (int r = 0; r < 4; ++r)
                    Cp[(long)(row0 + r) * ldc + col] = f2bf(acc[i][j][r] * inv[r]);
            }
        }
    }
}

// ---------------------------------------------------------------------------
// mega: ONE cooperative kernel, 512 blocks x 256 threads (2/CU, co-resident:
// 48KB LDS -> 3/CU possible; VGPR ~110). R16 theory: ~60-70 us of the 270 is
// inter-kernel launch/drain overhead (kernel-sum ~200 us from R0/R2 deltas);
// grid.sync() replaces 4 launch gaps. Stage bodies = measured-best R0 tiles.
// ---------------------------------------------------------------------------
struct MegaArgs {
    CastDesc cd; long total_quads;
    const u16 *Kbf, *Vbf, *Qbf, *Wkbf, *Wvbf, *Wobf;
    u16 *Kp, *VpT, *E, *Ctx;
    const float *bk, *bv, *bo;
    float* rsum;
    float* out;
};

__global__ __launch_bounds__(256, 2) void mega(MegaArgs a)
{
    __shared__ u16 lds[24576];           // 48 KB, shared by all stages
    u16* As = lds;
    const int u = blockIdx.x;

    // ---- stage 0: batched fp32->bf16 cast (grid-stride) + rsum zero
    {
        if (u < 16)
            a.rsum[u * 256 + threadIdx.x] = 0.f;
        for (long gi = (long)u * 256 + threadIdx.x; gi < a.total_quads;
             gi += (long)512 * 256) {
            int s = 0;
            while (gi >= a.cd.end[s]) ++s;
            const long start = (s == 0) ? 0 : a.cd.end[s - 1];
            const long q = gi - start;
            const float4 v = *(const float4*)(a.cd.src[s] + q * 4);
            ushort4 o;
            o.x = f2bf(v.x); o.y = f2bf(v.y); o.z = f2bf(v.z); o.w = f2bf(v.w);
            *(ushort4*)(a.cd.dst[s] + q * 4) = o;
        }
    }
    __threadfence();
    cg::this_grid().sync();

    // ---- stage 1: merged K/V projections, 256x128 tiles (64 blocks/z, z=8)
    {
        const int bz = u >> 6, inner = u & 63;
        const int bx = inner >> 3, by = inner & 7;        // nx=8, ny=8
        gemm_stage<256, 128, EPI_KV>(bx, by, bz,
            a.Kbf, a.Wkbf, a.Kp, a.bk, D2, D2, D2, D1,
            (long)LK * D2, 0L, (long)LK * D1, 1.0f,
            a.Vbf, a.Wvbf, a.VpT, a.bv, LK, (long)D1 * LK, nullptr,
            As, As + 256 * 64);
    }
    __threadfence();
    cg::this_grid().sync();

    // ---- stage 2: fused scores+exp, 128x128 tiles (128 blocks/z, z=4)
    {
        const int bz = u >> 7, inner = u & 127;
        const int bx = inner >> 3, by = inner & 7;        // nx=16, ny=8
        gemm_stage<128, 128, EPI_EXP>(bx, by, bz,
            a.Qbf, a.Kp, a.E, nullptr, D1, D1, D1, LK,
            (long)LQ * D1, (long)LK * D1, (long)LQ * LK, 0.03125f,
            nullptr, nullptr, nullptr, nullptr, 0, 0L, a.rsum,
            As, As + 128 * 64);
    }
    __threadfence();
    cg::this_grid().sync();

    // ---- stage 3: context + rowscale, 128x64 tiles (128 blocks/z, z=4)
    {
        const int bz = u >> 7, inner = u & 127;
        const int bx = inner >> 3, by = inner & 7;        // nx=16, ny=8
        gemm_stage<128, 64, EPI_ROWSCALE>(bx, by, bz,
            a.E, a.VpT, a.Ctx, nullptr, LK, LK, LK, D1,
            (long)LQ * LK, (long)D1 * LK, (long)LQ * D1, 1.0f,
            nullptr, nullptr, nullptr, nullptr, 0, 0L, a.rsum,
            As, As + 128 * 64);
    }
    __threadfence();
    cg::this_grid().sync();

    // ---- stage 4: out-proj, 128x64 tiles, M folds batches (512 blocks)
    {
        const int rest = u >> 3;
        const int bx = rest & 15, by = (u & 7) + 8 * (rest >> 4); // nx=16, ny=32
        gemm_stage<128, 64, EPI_F32_BIAS>(bx, by, 0,
            a.Ctx, a.Wobf, a.out, a.bo, D1, D1, D1, D1,
            0L, 0L, 0L, 1.0f,
            nullptr, nullptr, nullptr, nullptr, 0, 0L, nullptr,
            As, As + 128 * 64);
    }
}

// ---------------------------------------------------------------------------
// Fallback kernels (exact R0 path) if cooperative launch is unavailable.
// ---------------------------------------------------------------------------
__global__ __launch_bounds__(256) void cast6_kernel(CastDesc d, long total_quads,
                                                    float* __restrict__ rs0)
{
    if (blockIdx.x < 16)
        rs0[blockIdx.x * 256 + threadIdx.x] = 0.f;
    long gi = (long)blockIdx.x * 256 + threadIdx.x;
    if (gi >= total_quads) return;
    int s = 0;
    while (gi >= d.end[s]) ++s;
    const long start = (s == 0) ? 0 : d.end[s - 1];
    const long q = gi - start;
    const float4 v = *(const float4*)(d.src[s] + q * 4);
    ushort4 o;
    o.x = f2bf(v.x); o.y = f2bf(v.y); o.z = f2bf(v.z); o.w = f2bf(v.w);
    *(ushort4*)(d.dst[s] + q * 4) = o;
}

template <int BM, int BN, int EPI>
__global__ __launch_bounds__(256, 2) void mm_bf16(
    const u16* __restrict__ A, const u16* __restrict__ B,
    void* __restrict__ C, const float* __restrict__ bias,
    int nx, int Kd, int lda, int ldb, int ldc,
    long sA, long sB, long sC, float scale,
    const u16* __restrict__ A2, const u16* __restrict__ B2,
    void* __restrict__ C2, const float* __restrict__ bias2,
    int ldc2, long sC2, float* __restrict__ rsum)
{
    __shared__ u16 As[BM * 64];
    __shared__ u16 Bs[BN * 64];
    const int u    = blockIdx.x;
    const int rest = u >> 3;
    const int bx   = rest % nx;
    const int by   = (u & 7) + 8 * (rest / nx);
    gemm_stage<BM, BN, EPI>(bx, by, blockIdx.z, A, B, C, bias,
        Kd, lda, ldb, ldc, sA, sB, sC, scale,
        A2, B2, C2, bias2, ldc2, sC2, rsum, As, Bs);
}

// ---------------------------------------------------------------------------
extern "C" void kernel_launch(void* const* d_in, const int* in_sizes, int n_in,
                              void* d_out, int out_size, void* d_ws, size_t ws_size,
                              hipStream_t stream)
{
    const float* Q  = (const float*)d_in[0];
    const float* K  = (const float*)d_in[1];
    const float* V  = (const float*)d_in[2];
    const float* Wk = (const float*)d_in[3];
    const float* bk = (const float*)d_in[4];
    const float* Wv = (const float*)d_in[5];
    const float* bv = (const float*)d_in[6];
    const float* Wo = (const float*)d_in[7];
    const float* bo = (const float*)d_in[8];
    float* out = (float*)d_out;

    char* ws = (char*)d_ws;
    u16*   Kbf  = (u16*)(ws);
    u16*   Vbf  = (u16*)(ws + 22020096);
    u16*   Qbf  = (u16*)(ws + 44040192);
    u16*   Wkbf = (u16*)(ws + 52828160);
    u16*   Wvbf = (u16*)(ws + 55574528);
    u16*   Wobf = (u16*)(ws + 58320896);
    u16*   Kp   = (u16*)(ws + 60817408);
    u16*   VpT  = (u16*)(ws + 77594624);
    u16*   E    = (u16*)(ws);
    float* rsum = (float*)(ws + 94371840);
    u16*   Ctx  = Kp;

    const float inv_sqrt_d = 0.03125f;   // 1/sqrt(1024)

    CastDesc cd;
    cd.src[0] = K;  cd.dst[0] = Kbf;
    cd.src[1] = V;  cd.dst[1] = Vbf;
    cd.src[2] = Q;  cd.dst[2] = Qbf;
    cd.src[3] = Wk; cd.dst[3] = Wkbf;
    cd.src[4] = Wv; cd.dst[4] = Wvbf;
    cd.src[5] = Wo; cd.dst[5] = Wobf;
    long acc = 0;
    const long sizes[6] = {(long)BB*LK*D2, (long)BB*LK*D2, (long)BB*LQ*D1,
                           (long)D1*D2, (long)D1*D2, (long)D1*D1};
    for (int i = 0; i < 6; ++i) { acc += sizes[i] / 4; cd.end[i] = acc; }

    MegaArgs ma;
    ma.cd = cd; ma.total_quads = acc;
    ma.Kbf = Kbf; ma.Vbf = Vbf; ma.Qbf = Qbf;
    ma.Wkbf = Wkbf; ma.Wvbf = Wvbf; ma.Wobf = Wobf;
    ma.Kp = Kp; ma.VpT = VpT; ma.E = E; ma.Ctx = Ctx;
    ma.bk = bk; ma.bv = bv; ma.bo = bo;
    ma.rsum = rsum; ma.out = out;

    void* kargs[] = { (void*)&ma };
    hipError_t ce = hipLaunchCooperativeKernel(
        (const void*)mega, dim3(512), dim3(256), kargs, 0, stream);

    if (ce != hipSuccess) {
        (void)hipGetLastError();   // clear; fall back to the R0 5-kernel path
        cast6_kernel<<<dim3((unsigned)((acc + 255) / 256)), 256, 0, stream>>>(cd, acc, rsum);
        mm_bf16<256, 128, EPI_KV><<<dim3((D1/128)*(LK/256), 1, 2*BB), 256, 0, stream>>>(
            Kbf, Wkbf, Kp, bk, D1/128, D2, D2, D2, D1,
            (long)LK*D2, 0, (long)LK*D1, 1.0f,
            Vbf, Wvbf, VpT, bv, LK, (long)D1*LK, nullptr);
        mm_bf16<128, 128, EPI_EXP><<<dim3((LK/128)*(LQ/128), 1, BB), 256, 0, stream>>>(
            Qbf, Kp, E, nullptr, LK/128, D1, D1, D1, LK,
            (long)LQ*D1, (long)LK*D1, (long)LQ*LK, inv_sqrt_d,
            nullptr, nullptr, nullptr, nullptr, 0, 0, rsum);
        mm_bf16<128, 64, EPI_ROWSCALE><<<dim3((D1/64)*(LQ/128), 1, BB), 256, 0, stream>>>(
            E, VpT, Ctx, nullptr, D1/64, LK, LK, LK, D1,
            (long)LQ*LK, (long)D1*LK, (long)LQ*D1, 1.0f,
            nullptr, nullptr, nullptr, nullptr, 0, 0, rsum);
        mm_bf16<128, 64, EPI_F32_BIAS><<<dim3((D1/64)*((BB*LQ)/128), 1, 1), 256, 0, stream>>>(
            Ctx, Wobf, out, bo, D1/64, D1, D1, D1, D1, 0, 0, 0, 1.0f,
            nullptr, nullptr, nullptr, nullptr, 0, 0, nullptr);
    }
}

// Round 7
// 306.386 us; speedup vs baseline: 2.5469x; 2.5469x over previous
//
#include <hip/hip_runtime.h>

// Problem dims (fixed)
#define BB   4
#define LQ   1024
#define LK   2048
#define D1   1024
#define D2   1280

typedef unsigned short u16;
typedef __attribute__((ext_vector_type(8))) short   short8;   // 8 bf16 = 4 VGPRs
typedef __attribute__((ext_vector_type(4))) float   floatx4;  // MFMA accum

__device__ __forceinline__ u16 f2bf(float f) {
    unsigned u = __float_as_uint(f);
    unsigned r = (u + 0x7FFFu + ((u >> 16) & 1u)) >> 16;   // RNE
    return (u16)r;
}

// HW packed fp32->bf16 (RNE, bit-identical to f2bf for normals). T12 recipe:
// no builtin on gfx950, inline asm; non-volatile so the scheduler may move it.
__device__ __forceinline__ unsigned cvt_pk_bf16(float lo, float hi) {
    unsigned r;
    asm("v_cvt_pk_bf16_f32 %0, %1, %2" : "=v"(r) : "v"(lo), "v"(hi));
    return r;
}

// async global->LDS, 16B per lane; LDS dest = wave-uniform base + lane*16
__device__ __forceinline__ void gl_lds16(const void* g, void* l) {
    __builtin_amdgcn_global_load_lds(
        (const __attribute__((address_space(1))) unsigned int*)g,
        (__attribute__((address_space(3))) unsigned int*)l, 16, 0, 0);
}

// ---------------------------------------------------------------------------
// Batched fp32 -> bf16 cast. R16/R17: only {Q, Wk, Wv, Wo} — K,V conversion
// is fused into mm_kv's A-staging (their bf16 copies had no other consumer).
// Traffic 173 MB -> 47 MB. Also zeroes rsum.
// ---------------------------------------------------------------------------
struct CastDesc {
    const float* src[6];
    u16*         dst[6];
    long         end[6];      // cumulative end in QUADS (4 elems)
};

__global__ __launch_bounds__(256) void cast6_kernel(CastDesc d, long total_quads,
                                                    float* __restrict__ rs0)
{
    if (blockIdx.x < 16)
        rs0[blockIdx.x * 256 + threadIdx.x] = 0.f;   // 16*256 = 4096 = BB*LQ

    long gi = (long)blockIdx.x * 256 + threadIdx.x;
    if (gi >= total_quads) return;
    int s = 0;
    while (gi >= d.end[s]) ++s;
    const long start = (s == 0) ? 0 : d.end[s - 1];
    const long q = gi - start;
    const float4 v = *(const float4*)(d.src[s] + q * 4);
    ushort4 o;
    o.x = f2bf(v.x); o.y = f2bf(v.y); o.z = f2bf(v.z); o.w = f2bf(v.w);
    *(ushort4*)(d.dst[s] + q * 4) = o;
}

enum { EPI_F32_BIAS, EPI_KV, EPI_EXP, EPI_ROWSCALE };

// ---------------------------------------------------------------------------
// mm_kv: merged K/V projection with FUSED fp32->bf16 A-conversion.
// Structure = measured-best 2-phase 256x128 TALL kernel, except A-staging is
// reg-staged (global_load_dwordx4 x2 -> v_cvt_pk_bf16_f32 x4 -> ds_write_b128)
// because global_load_lds cannot convert. Same slot-linear swizzled LDS
// layout as the gl_lds16 path (source chunk (idx&7)^(mr&7); read side
// unchanged). B (weights, bf16 from cast) still uses global_load_lds.
// Race audit: stage -> sync -> compute -> sync; syncthreads drains lgkm+vm,
// so prior-iter ds_reads precede next-iter ds_writes. Barriers uniform.
// ---------------------------------------------------------------------------
__global__ __launch_bounds__(256, 2) void mm_kv(
    const float* __restrict__ Kf, const u16* __restrict__ Wkb,
    u16* __restrict__ Kp, const float* __restrict__ bk,
    const float* __restrict__ Vf, const u16* __restrict__ Wvb,
    u16* __restrict__ VpT, const float* __restrict__ bv)
{
    constexpr int BM = 256, BN = 128, NJ = 8, AISS = 8, NBI = 4;
    __shared__ u16 As[BM * 64];      // 32 KB, [m][k] swizzled bf16
    __shared__ u16 Bs[BN * 64];      // 16 KB

    // decode: grid.x = 64 (nx=8, ny=8), z = 8
    const int u    = blockIdx.x;
    const int bx   = (u >> 3) & 7;
    const int by   = u & 7;

    const int  bz  = blockIdx.z;
    const bool isV = (bz >= BB);
    const int  b   = isV ? bz - BB : bz;

    const float* Ab = (isV ? Vf : Kf) + (long)b * ((long)LK * D2) + (long)by * BM * D2;
    const u16*   Bb = (isV ? Wvb : Wkb) + (long)bx * BN * D2;

    const int t    = threadIdx.x;
    const int w    = t >> 6;              // wave 0..3
    const int l    = t & 63;
    const int l16  = l & 15;
    const int quad = l >> 4;
    const int wm   = w * 64;              // TALL: waves stacked in M
    const int wn   = 0;

    floatx4 acc[4][NJ];
    #pragma unroll
    for (int i = 0; i < 4; ++i)
        #pragma unroll
        for (int j = 0; j < NJ; ++j)
            acc[i][j] = (floatx4){0.f, 0.f, 0.f, 0.f};

    for (int k0 = 0; k0 < D2; k0 += 64) {
        // ---- A: fp32 global -> regs -> cvt_pk -> swizzled LDS (bf16)
        #pragma unroll
        for (int c = 0; c < AISS; ++c) {
            const int idx = (w * AISS + c) * 64 + l;     // slot 0..2047
            const int mr  = idx >> 3;                    // row 0..255
            const int kq  = (idx & 7) ^ (mr & 7);        // source chunk
            const float* sp = Ab + (long)mr * D2 + k0 + kq * 8;
            const float4 v0 = *(const float4*)sp;
            const float4 v1 = *(const float4*)(sp + 4);
            uint4 pk;
            pk.x = cvt_pk_bf16(v0.x, v0.y);
            pk.y = cvt_pk_bf16(v0.z, v0.w);
            pk.z = cvt_pk_bf16(v1.x, v1.y);
            pk.w = cvt_pk_bf16(v1.z, v1.w);
            *(uint4*)(As + idx * 8) = pk;                // ds_write_b128
        }
        // ---- B: bf16 weights, async global->LDS (pre-swizzled source)
        #pragma unroll
        for (int c = 0; c < NBI; ++c) {
            const int idx = (w * NBI + c) * 64 + l;
            const int mr  = idx >> 3;
            const int kq  = (idx & 7) ^ (mr & 7);
            gl_lds16(Bb + (long)mr * D2 + k0 + kq * 8, (char*)Bs + (w * NBI + c) * 1024);
        }
        __syncthreads();

        #pragma unroll
        for (int q = 0; q < 2; ++q) {
            const int sc = ((q * 4 + quad) ^ (l & 7)) * 8;
            short8 af[4], bfr[NJ];
            #pragma unroll
            for (int i = 0; i < 4; ++i)
                af[i]  = *(const short8*)(As + (wm + i * 16 + l16) * 64 + sc);
            #pragma unroll
            for (int j = 0; j < NJ; ++j)
                bfr[j] = *(const short8*)(Bs + (wn + j * 16 + l16) * 64 + sc);
            #pragma unroll
            for (int i = 0; i < 4; ++i)
                #pragma unroll
                for (int j = 0; j < NJ; ++j)
                    acc[i][j] = __builtin_amdgcn_mfma_f32_16x16x32_bf16(
                        af[i], bfr[j], acc[i][j], 0, 0, 0);
        }
        __syncthreads();
    }

    // ---- epilogue (C/D layout: col = lane&15, row = quad*4 + reg)
    const int mb = by * BM + wm;
    const int nb = bx * BN + wn;

    if (!isV) {        // K-proj: row-major bf16 + bias
        u16* Cp = Kp + (long)b * ((long)LK * D1);
        #pragma unroll
        for (int i = 0; i < 4; ++i)
            #pragma unroll
            for (int j = 0; j < NJ; ++j) {
                const int col  = nb + j * 16 + l16;
                const int row0 = mb + i * 16 + quad * 4;
                const float bs = bk[col];
                #pragma unroll
                for (int r = 0; r < 4; ++r)
                    Cp[(long)(row0 + r) * D1 + col] = f2bf(acc[i][j][r] + bs);
            }
    } else {           // V-proj: transposed store VpT[col][row0..+3]
        u16* Cp = VpT + (long)b * ((long)D1 * LK);
        #pragma unroll
        for (int i = 0; i < 4; ++i)
            #pragma unroll
            for (int j = 0; j < NJ; ++j) {
                const int col  = nb + j * 16 + l16;
                const int row0 = mb + i * 16 + quad * 4;
                const float bs = bv[col];
                const floatx4 vv = acc[i][j];
                ushort4 pkk;
                pkk.x = f2bf(vv[0] + bs); pkk.y = f2bf(vv[1] + bs);
                pkk.z = f2bf(vv[2] + bs); pkk.w = f2bf(vv[3] + bs);
                *(ushort4*)(Cp + (long)col * LK + row0) = pkk;
            }
    }
}

// ---------------------------------------------------------------------------
// mm_bf16: m97-style 2-barrier GEMM (measured-best tiles, R0 config) for
// scores (EPI_EXP 128x128), ctx (EPI_ROWSCALE 128x64), out (EPI_F32_BIAS
// 128x64). R4 proved 128x128 for ctx/out regresses (grid 256 = 1 block/CU).
// ---------------------------------------------------------------------------
template <int BM, int BN, int EPI>
__global__ __launch_bounds__(256, 2) void mm_bf16(
    const u16* __restrict__ A, const u16* __restrict__ B,
    void* __restrict__ C, const float* __restrict__ bias,
    int nx, int Kd, int lda, int ldb, int ldc,
    long sA, long sB, long sC, float scale,
    float* __restrict__ rsum)
{
    constexpr int NJ  = BN / 32;      // j-frags per wave (2x2 wave grid)
    constexpr int AISS = BM / 32;
    constexpr int NBI  = BN / 32;

    __shared__ u16 As[BM * 64];
    __shared__ u16 Bs[BN * 64];

    const int u    = blockIdx.x;
    const int rest = u >> 3;
    const int bx   = rest % nx;
    const int by   = (u & 7) + 8 * (rest / nx);

    const int bz = blockIdx.z;
    const u16* Ab = A + (long)bz * sA + (long)by * BM * lda;
    const u16* Bb = B + (long)bz * sB + (long)bx * BN * ldb;

    const int t    = threadIdx.x;
    const int w    = t >> 6;
    const int l    = t & 63;
    const int l16  = l & 15;
    const int quad = l >> 4;
    const int wm   = (w >> 1) * 64;
    const int wn   = (w & 1) * (BN / 2);

    floatx4 acc[4][NJ];
    #pragma unroll
    for (int i = 0; i < 4; ++i)
        #pragma unroll
        for (int j = 0; j < NJ; ++j)
            acc[i][j] = (floatx4){0.f, 0.f, 0.f, 0.f};

    for (int k0 = 0; k0 < Kd; k0 += 64) {
        #pragma unroll
        for (int c = 0; c < AISS; ++c) {
            const int idx = (w * AISS + c) * 64 + l;
            const int mr  = idx >> 3;
            const int kq  = (idx & 7) ^ (mr & 7);
            gl_lds16(Ab + (long)mr * lda + k0 + kq * 8, (char*)As + (w * AISS + c) * 1024);
        }
        #pragma unroll
        for (int c = 0; c < NBI; ++c) {
            const int idx = (w * NBI + c) * 64 + l;
            const int mr  = idx >> 3;
            const int kq  = (idx & 7) ^ (mr & 7);
            gl_lds16(Bb + (long)mr * ldb + k0 + kq * 8, (char*)Bs + (w * NBI + c) * 1024);
        }
        __syncthreads();

        #pragma unroll
        for (int q = 0; q < 2; ++q) {
            const int sc = ((q * 4 + quad) ^ (l & 7)) * 8;
            short8 af[4], bfr[NJ];
            #pragma unroll
            for (int i = 0; i < 4; ++i)
                af[i]  = *(const short8*)(As + (wm + i * 16 + l16) * 64 + sc);
            #pragma unroll
            for (int j = 0; j < NJ; ++j)
                bfr[j] = *(const short8*)(Bs + (wn + j * 16 + l16) * 64 + sc);
            #pragma unroll
            for (int i = 0; i < 4; ++i)
                #pragma unroll
                for (int j = 0; j < NJ; ++j)
                    acc[i][j] = __builtin_amdgcn_mfma_f32_16x16x32_bf16(
                        af[i], bfr[j], acc[i][j], 0, 0, 0);
        }
        __syncthreads();
    }

    const int mb = by * BM + wm;
    const int nb = bx * BN + wn;

    if (EPI == EPI_F32_BIAS) {
        float* Cp = (float*)C + (long)bz * sC;
        #pragma unroll
        for (int i = 0; i < 4; ++i)
            #pragma unroll
            for (int j = 0; j < NJ; ++j) {
                const int col  = nb + j * 16 + l16;
                const int row0 = mb + i * 16 + quad * 4;
                const float bs = bias[col];
                #pragma unroll
                for (int r = 0; r < 4; ++r)
                    Cp[(long)(row0 + r) * ldc + col] = acc[i][j][r] + bs;
            }
    } else if (EPI == EPI_EXP) {
        u16* Cp = (u16*)C + (long)bz * sC;
        float lsum[4][4];
        #pragma unroll
        for (int i = 0; i < 4; ++i)
            #pragma unroll
            for (int r = 0; r < 4; ++r)
                lsum[i][r] = 0.f;
        #pragma unroll
        for (int i = 0; i < 4; ++i)
            #pragma unroll
            for (int j = 0; j < NJ; ++j) {
                const int col  = nb + j * 16 + l16;
                const int row0 = mb + i * 16 + quad * 4;
                #pragma unroll
                for (int r = 0; r < 4; ++r) {
                    const float e = __expf(acc[i][j][r] * scale);
                    Cp[(long)(row0 + r) * ldc + col] = f2bf(e);
                    lsum[i][r] += e;
                }
            }
        float* rp = rsum + (long)bz * LQ;
        #pragma unroll
        for (int i = 0; i < 4; ++i)
            #pragma unroll
            for (int r = 0; r < 4; ++r) {
                float s = lsum[i][r];
                s += __shfl_xor(s, 1);
                s += __shfl_xor(s, 2);
                s += __shfl_xor(s, 4);
                s += __shfl_xor(s, 8);
                if (l16 == 0)
                    atomicAdd(rp + mb + i * 16 + quad * 4 + r, s);
            }
    } else { // EPI_ROWSCALE
        u16* Cp = (u16*)C + (long)bz * sC;
        const float* rp = rsum + (long)bz * LQ;
        #pragma unroll
        for (int i = 0; i < 4; ++i) {
            const int row0 = mb + i * 16 + quad * 4;
            float inv[4];
            #pragma unroll
            for (int r = 0; r < 4; ++r)
                inv[r] = 1.0f / rp[row0 + r];
            #pragma unroll
            for (int j = 0; j < NJ; ++j) {
                const int col = nb + j * 16 + l16;
                #pragma unroll
                for (int r = 0; r < 4; ++r)
                    Cp[(long)(row0 + r) * ldc + col] = f2bf(acc[i][j][r] * inv[r]);
            }
        }
    }
}

// ---------------------------------------------------------------------------
extern "C" void kernel_launch(void* const* d_in, const int* in_sizes, int n_in,
                              void* d_out, int out_size, void* d_ws, size_t ws_size,
                              hipStream_t stream)
{
    const float* Q  = (const float*)d_in[0];
    const float* K  = (const float*)d_in[1];
    const float* V  = (const float*)d_in[2];
    const float* Wk = (const float*)d_in[3];
    const float* bk = (const float*)d_in[4];
    const float* Wv = (const float*)d_in[5];
    const float* bv = (const float*)d_in[6];
    const float* Wo = (const float*)d_in[7];
    const float* bo = (const float*)d_in[8];
    float* out = (float*)d_out;

    // Workspace layout (Kbf/Vbf regions now unused; E starts at 0):
    char* ws = (char*)d_ws;
    u16*   Qbf  = (u16*)(ws + 44040192);
    u16*   Wkbf = (u16*)(ws + 52828160);
    u16*   Wvbf = (u16*)(ws + 55574528);
    u16*   Wobf = (u16*)(ws + 58320896);
    u16*   Kp   = (u16*)(ws + 60817408);
    u16*   VpT  = (u16*)(ws + 77594624);
    u16*   E    = (u16*)(ws);
    float* rsum = (float*)(ws + 94371840);
    u16*   Ctx  = Kp;

    const float inv_sqrt_d = 0.03125f;   // 1/sqrt(1024)

    // ---- cast Q + weights only (K,V conversion fused into mm_kv)
    CastDesc cd;
    cd.src[0] = Q;  cd.dst[0] = Qbf;
    cd.src[1] = Wk; cd.dst[1] = Wkbf;
    cd.src[2] = Wv; cd.dst[2] = Wvbf;
    cd.src[3] = Wo; cd.dst[3] = Wobf;
    cd.src[4] = Wo; cd.dst[4] = Wobf;   // unused (end[4]=end[5]=total)
    cd.src[5] = Wo; cd.dst[5] = Wobf;
    long acc = 0;
    const long sizes[4] = {(long)BB*LQ*D1, (long)D1*D2, (long)D1*D2, (long)D1*D1};
    for (int i = 0; i < 4; ++i) { acc += sizes[i] / 4; cd.end[i] = acc; }
    cd.end[4] = acc; cd.end[5] = acc;
    cast6_kernel<<<dim3((unsigned)((acc + 255) / 256)), 256, 0, stream>>>(cd, acc, rsum);

    // ---- merged K/V projections with fused fp32->bf16 A-staging
    // grid 64 x z=8 = 512 blocks, 2/CU
    mm_kv<<<dim3(64, 1, 2*BB), 256, 0, stream>>>(
        K, Wkbf, Kp, bk, V, Wvbf, VpT, bv);

    // ---- fused scores+exp: 128x128, 512 blocks
    mm_bf16<128, 128, EPI_EXP><<<dim3((LK/128)*(LQ/128), 1, BB), 256, 0, stream>>>(
        Qbf, Kp, E, nullptr, LK/128, D1, D1, D1, LK,
        (long)LQ*D1, (long)LK*D1, (long)LQ*LK, inv_sqrt_d, rsum);

    // ---- context with fused normalization: Ctx = (E @ VpT^T) / rsum[row]
    mm_bf16<128, 64, EPI_ROWSCALE><<<dim3((D1/64)*(LQ/128), 1, BB), 256, 0, stream>>>(
        E, VpT, Ctx, nullptr, D1/64, LK, LK, LK, D1,
        (long)LQ*LK, (long)D1*LK, (long)LQ*D1, 1.0f, rsum);

    // ---- output: out = Ctx @ Wo^T + bo
    mm_bf16<128, 64, EPI_F32_BIAS><<<dim3((D1/64)*((BB*LQ)/128), 1, 1), 256, 0, stream>>>(
        Ctx, Wobf, out, bo, D1/64, D1, D1, D1, D1, 0, 0, 0, 1.0f, rsum);
}

// Round 8
// 276.004 us; speedup vs baseline: 2.8273x; 1.1101x over previous
//
#include <hip/hip_runtime.h>

// Problem dims (fixed)
#define BB   4
#define LQ   1024
#define LK   2048
#define D1   1024
#define D2   1280

typedef unsigned short u16;
typedef __attribute__((ext_vector_type(8))) short   short8;   // 8 bf16 = 4 VGPRs
typedef __attribute__((ext_vector_type(4))) float   floatx4;  // MFMA accum

__device__ __forceinline__ u16 f2bf(float f) {
    unsigned u = __float_as_uint(f);
    unsigned r = (u + 0x7FFFu + ((u >> 16) & 1u)) >> 16;   // RNE
    return (u16)r;
}

// async global->LDS, 16B per lane; LDS dest = wave-uniform base + lane*16
__device__ __forceinline__ void gl_lds16(const void* g, void* l) {
    __builtin_amdgcn_global_load_lds(
        (const __attribute__((address_space(1))) unsigned int*)g,
        (__attribute__((address_space(3))) unsigned int*)l, 16, 0, 0);
}

// ---------------------------------------------------------------------------
// Batched fp32 -> bf16 cast: 6 tensors, ONE launch. R18: same 1-quad body as
// the R7-measured-fastest form (44 us), but GRID-STRIDE at 3468 blocks
// instead of 27740 one-shot blocks (guideline 11: cap ~2-4K blocks) —
// targets the dispatch-ramp share of the 44-17=17 us gap to the BW floor.
// R8 (4-quad) / R11 (16B-store) changed the inner shape and lost to
// in-thread load serialization; this keeps 1 load in flight per thread.
// Also zeroes the 4096-float rowsum array (blocks 0..15).
// R7 lesson (fused-cast): reg-staged fp32->bf16 inside the GEMM exposes HBM
// latency that gl_lds16 hides — standalone cast is the right structure.
// ---------------------------------------------------------------------------
struct CastDesc {
    const float* src[6];
    u16*         dst[6];
    long         end[6];      // cumulative end in QUADS (4 elems)
};

#define CAST_BLOCKS 3468

__global__ __launch_bounds__(256) void cast6_kernel(CastDesc d, long total_quads,
                                                    float* __restrict__ rs0)
{
    if (blockIdx.x < 16)
        rs0[blockIdx.x * 256 + threadIdx.x] = 0.f;   // 16*256 = 4096 = BB*LQ

    for (long gi = (long)blockIdx.x * 256 + threadIdx.x; gi < total_quads;
         gi += (long)CAST_BLOCKS * 256) {
        int s = 0;
        while (gi >= d.end[s]) ++s;        // 6 segments, short loop
        const long start = (s == 0) ? 0 : d.end[s - 1];
        const long q = gi - start;
        const float4 v = *(const float4*)(d.src[s] + q * 4);
        ushort4 o;
        o.x = f2bf(v.x); o.y = f2bf(v.y); o.z = f2bf(v.z); o.w = f2bf(v.w);
        *(ushort4*)(d.dst[s] + q * 4) = o;
    }
}

// ---------------------------------------------------------------------------
// bf16 MFMA GEMM, operands in [rows][K] layout (B is N x K, i.e. x @ W^T):
//   C[bz][m][n] = epi( sum_k A[bz][m][k] * B[bz][n][k] )
// BM x BN tile, BK=64, 256 threads = 4 waves, 16x16x32 MFMA,
// global_load_lds(16B) staging, XOR-swizzled LDS (conflicts = 0 measured),
// XCD-aware flattened grid. ny % 8 == 0.
// This is the R0-champion configuration (270.3 us) restored verbatim:
// R13/R14 8-phase = null x2; R15 ctx/out 128x128 = regress (1 block/CU);
// R16 mega grid-sync = -510 us; R17 fused cast = -36 us.
// ---------------------------------------------------------------------------
enum { EPI_F32_BIAS, EPI_KV, EPI_EXP, EPI_ROWSCALE };

template <int BM, int BN, int EPI>
__global__ __launch_bounds__(256, 2) void mm_bf16(
    const u16* __restrict__ A, const u16* __restrict__ B,
    void* __restrict__ C, const float* __restrict__ bias,
    int nx, int Kd, int lda, int ldb, int ldc,
    long sA, long sB, long sC, float scale,
    const u16* __restrict__ A2, const u16* __restrict__ B2,
    void* __restrict__ C2, const float* __restrict__ bias2,
    int ldc2, long sC2, float* __restrict__ rsum)
{
    constexpr bool TALL = (BM == 256);
    constexpr int  NJ   = TALL ? (BN / 16) : (BN / 32);  // j-frags per wave
    constexpr int  AISS = BM / 32;    // A staging issues per thread
    constexpr int  NBI  = BN / 32;    // B staging issues per thread

    __shared__ u16 As[BM * 64];      // [m][k] swizzled (16/32 KB)
    __shared__ u16 Bs[BN * 64];      // [n][k] swizzled (8/16 KB)

    const int u    = blockIdx.x;
    const int rest = u >> 3;
    const int bx   = rest % nx;
    const int by   = (u & 7) + 8 * (rest / nx);

    const int  bz  = blockIdx.z;
    const bool isV = (EPI == EPI_KV) && (bz >= BB);
    const int  b   = isV ? bz - BB : bz;

    const u16* Ab = (isV ? A2 : A) + (long)b * sA + (long)by * BM * lda;
    const u16* Bb = (isV ? B2 : B) + (long)b * sB + (long)bx * BN * ldb;

    const int t    = threadIdx.x;
    const int w    = t >> 6;              // wave 0..3
    const int l    = t & 63;
    const int l16  = l & 15;
    const int quad = l >> 4;
    const int wm   = TALL ? w * 64 : (w >> 1) * 64;   // wave origin in tile
    const int wn   = TALL ? 0      : (w & 1) * (BN / 2);

    floatx4 acc[4][NJ];
    #pragma unroll
    for (int i = 0; i < 4; ++i)
        #pragma unroll
        for (int j = 0; j < NJ; ++j)
            acc[i][j] = (floatx4){0.f, 0.f, 0.f, 0.f};

    for (int k0 = 0; k0 < Kd; k0 += 64) {
        // ---- stage A (BMx64) and B (BNx64), XOR-swizzled source
        #pragma unroll
        for (int c = 0; c < AISS; ++c) {
            const int idx = (w * AISS + c) * 64 + l;  // slot
            const int mr  = idx >> 3;                 // row 0..BM-1
            const int kq  = (idx & 7) ^ (mr & 7);     // global chunk for slot
            gl_lds16(Ab + (long)mr * lda + k0 + kq * 8, (char*)As + (w * AISS + c) * 1024);
        }
        #pragma unroll
        for (int c = 0; c < NBI; ++c) {
            const int idx = (w * NBI + c) * 64 + l;
            const int mr  = idx >> 3;
            const int kq  = (idx & 7) ^ (mr & 7);
            gl_lds16(Bb + (long)mr * ldb + k0 + kq * 8, (char*)Bs + (w * NBI + c) * 1024);
        }
        __syncthreads();

        // ---- 2 x K=32 MFMA steps; fragment chunk = (q*4+quad)^(l&7)
        #pragma unroll
        for (int q = 0; q < 2; ++q) {
            const int sc = ((q * 4 + quad) ^ (l & 7)) * 8;   // swizzled elem off
            short8 af[4], bfr[NJ];
            #pragma unroll
            for (int i = 0; i < 4; ++i)
                af[i]  = *(const short8*)(As + (wm + i * 16 + l16) * 64 + sc);
            #pragma unroll
            for (int j = 0; j < NJ; ++j)
                bfr[j] = *(const short8*)(Bs + (wn + j * 16 + l16) * 64 + sc);
            #pragma unroll
            for (int i = 0; i < 4; ++i)
                #pragma unroll
                for (int j = 0; j < NJ; ++j)
                    acc[i][j] = __builtin_amdgcn_mfma_f32_16x16x32_bf16(
                        af[i], bfr[j], acc[i][j], 0, 0, 0);
        }
        __syncthreads();
    }

    // ---- epilogue: C/D layout col = lane&15, row = quad*4 + reg
    const int mb = by * BM + wm;
    const int nb = bx * BN + wn;

    if (EPI == EPI_F32_BIAS) {
        float* Cp = (float*)C + (long)bz * sC;
        #pragma unroll
        for (int i = 0; i < 4; ++i)
            #pragma unroll
            for (int j = 0; j < NJ; ++j) {
                const int col  = nb + j * 16 + l16;
                const int row0 = mb + i * 16 + quad * 4;
                const float bs = bias[col];
                #pragma unroll
                for (int r = 0; r < 4; ++r)
                    Cp[(long)(row0 + r) * ldc + col] = acc[i][j][r] + bs;
            }
    } else if (EPI == EPI_KV) {
        if (!isV) {        // K-proj: row-major bf16 + bias
            u16* Cp = (u16*)C + (long)b * sC;
            #pragma unroll
            for (int i = 0; i < 4; ++i)
                #pragma unroll
                for (int j = 0; j < NJ; ++j) {
                    const int col  = nb + j * 16 + l16;
                    const int row0 = mb + i * 16 + quad * 4;
                    const float bs = bias[col];
                    #pragma unroll
                    for (int r = 0; r < 4; ++r)
                        Cp[(long)(row0 + r) * ldc + col] = f2bf(acc[i][j][r] + bs);
                }
        } else {           // V-proj: transposed store C2^T[col][row0..+3]
            u16* Cp = (u16*)C2 + (long)b * sC2;
            #pragma unroll
            for (int i = 0; i < 4; ++i)
                #pragma unroll
                for (int j = 0; j < NJ; ++j) {
                    const int col  = nb + j * 16 + l16;
                    const int row0 = mb + i * 16 + quad * 4;
                    const float bs = bias2[col];
                    const floatx4 v = acc[i][j];
                    ushort4 pk;
                    pk.x = f2bf(v[0] + bs); pk.y = f2bf(v[1] + bs);
                    pk.z = f2bf(v[2] + bs); pk.w = f2bf(v[3] + bs);
                    *(ushort4*)(Cp + (long)col * ldc2 + row0) = pk;
                }
        }
    } else if (EPI == EPI_EXP) {
        // E = bf16(exp(acc*scale)); accumulate per-row sums -> atomicAdd
        u16* Cp = (u16*)C + (long)bz * sC;
        float lsum[4][4];
        #pragma unroll
        for (int i = 0; i < 4; ++i)
            #pragma unroll
            for (int r = 0; r < 4; ++r)
                lsum[i][r] = 0.f;
        #pragma unroll
        for (int i = 0; i < 4; ++i)
            #pragma unroll
            for (int j = 0; j < NJ; ++j) {
                const int col  = nb + j * 16 + l16;
                const int row0 = mb + i * 16 + quad * 4;
                #pragma unroll
                for (int r = 0; r < 4; ++r) {
                    const float e = __expf(acc[i][j][r] * scale);
                    Cp[(long)(row0 + r) * ldc + col] = f2bf(e);
                    lsum[i][r] += e;
                }
            }
        // reduce across the 16 l16-lanes of each quad, one atomic per row
        float* rp = rsum + (long)bz * LQ;
        #pragma unroll
        for (int i = 0; i < 4; ++i)
            #pragma unroll
            for (int r = 0; r < 4; ++r) {
                float s = lsum[i][r];
                s += __shfl_xor(s, 1);
                s += __shfl_xor(s, 2);
                s += __shfl_xor(s, 4);
                s += __shfl_xor(s, 8);
                if (l16 == 0)
                    atomicAdd(rp + mb + i * 16 + quad * 4 + r, s);
            }
    } else { // EPI_ROWSCALE: bf16(acc / rowsum[row])
        u16* Cp = (u16*)C + (long)bz * sC;
        const float* rp = rsum + (long)bz * LQ;
        #pragma unroll
        for (int i = 0; i < 4; ++i) {
            const int row0 = mb + i * 16 + quad * 4;
            float inv[4];
            #pragma unroll
            for (int r = 0; r < 4; ++r)
                inv[r] = 1.0f / rp[row0 + r];
            #pragma unroll
            for (int j = 0; j < NJ; ++j) {
                const int col = nb + j * 16 + l16;
                #pragma unroll
                for (int r = 0; r < 4; ++r)
                    Cp[(long)(row0 + r) * ldc + col] = f2bf(acc[i][j][r] * inv[r]);
            }
        }
    }
}

// ---------------------------------------------------------------------------
extern "C" void kernel_launch(void* const* d_in, const int* in_sizes, int n_in,
                              void* d_out, int out_size, void* d_ws, size_t ws_size,
                              hipStream_t stream)
{
    const float* Q  = (const float*)d_in[0];
    const float* K  = (const float*)d_in[1];
    const float* V  = (const float*)d_in[2];
    const float* Wk = (const float*)d_in[3];
    const float* bk = (const float*)d_in[4];
    const float* Wv = (const float*)d_in[5];
    const float* bv = (const float*)d_in[6];
    const float* Wo = (const float*)d_in[7];
    const float* bo = (const float*)d_in[8];
    float* out = (float*)d_out;

    // Workspace layout (max extent 94.4 MB + 16 KB):
    //   Kbf  [0.0, 22.0)M   dead after KV-proj; E aliases its head
    //   Vbf  [22.0, 44.0)M  dead after KV-proj
    //   Qbf  [44.0, 52.4)M  dead after scores
    //   Wkbf/Wvbf/Wobf [52.8, 60.4)M
    //   Kp   [60.8, 77.6)M  dead after scores; Ctx aliases it
    //   VpT  [77.6, 94.4)M
    //   E    [0.0, 16.8)M   bf16 exp-scores (aliases dead Kbf)
    //   rsum [94.4M, +16K)  fp32 per-row exp sums
    char* ws = (char*)d_ws;
    u16*   Kbf  = (u16*)(ws);
    u16*   Vbf  = (u16*)(ws + 22020096);
    u16*   Qbf  = (u16*)(ws + 44040192);
    u16*   Wkbf = (u16*)(ws + 52828160);
    u16*   Wvbf = (u16*)(ws + 55574528);
    u16*   Wobf = (u16*)(ws + 58320896);
    u16*   Kp   = (u16*)(ws + 60817408);
    u16*   VpT  = (u16*)(ws + 77594624);
    u16*   E    = (u16*)(ws);
    float* rsum = (float*)(ws + 94371840);
    u16*   Ctx  = Kp;

    const float inv_sqrt_d = 0.03125f;   // 1/sqrt(1024)

    // ---- one batched cast launch (also zeroes rsum), grid-stride 3468 blocks
    CastDesc cd;
    cd.src[0] = K;  cd.dst[0] = Kbf;
    cd.src[1] = V;  cd.dst[1] = Vbf;
    cd.src[2] = Q;  cd.dst[2] = Qbf;
    cd.src[3] = Wk; cd.dst[3] = Wkbf;
    cd.src[4] = Wv; cd.dst[4] = Wvbf;
    cd.src[5] = Wo; cd.dst[5] = Wobf;
    long acc = 0;
    const long sizes[6] = {(long)BB*LK*D2, (long)BB*LK*D2, (long)BB*LQ*D1,
                           (long)D1*D2, (long)D1*D2, (long)D1*D1};
    for (int i = 0; i < 6; ++i) { acc += sizes[i] / 4; cd.end[i] = acc; }
    cast6_kernel<<<dim3(CAST_BLOCKS), 256, 0, stream>>>(cd, acc, rsum);

    // ---- merged K/V projections, 256x128 tiles, z=8, nx=8, ny=8 (512 blocks)
    mm_bf16<256, 128, EPI_KV><<<dim3((D1/128)*(LK/256), 1, 2*BB), 256, 0, stream>>>(
        Kbf, Wkbf, Kp, bk, D1/128, D2, D2, D2, D1,
        (long)LK*D2, 0, (long)LK*D1, 1.0f,
        Vbf, Wvbf, VpT, bv, LK, (long)D1*LK, nullptr);

    // ---- fused scores+exp: E[b][q][k] = exp(Q@Kp^T / 32), rsum += row sums
    mm_bf16<128, 128, EPI_EXP><<<dim3((LK/128)*(LQ/128), 1, BB), 256, 0, stream>>>(
        Qbf, Kp, E, nullptr, LK/128, D1, D1, D1, LK,
        (long)LQ*D1, (long)LK*D1, (long)LQ*LK, inv_sqrt_d,
        nullptr, nullptr, nullptr, nullptr, 0, 0, rsum);

    // ---- context with fused normalization: Ctx = (E @ VpT^T) / rsum[row]
    mm_bf16<128, 64, EPI_ROWSCALE><<<dim3((D1/64)*(LQ/128), 1, BB), 256, 0, stream>>>(
        E, VpT, Ctx, nullptr, D1/64, LK, LK, LK, D1,
        (long)LQ*LK, (long)D1*LK, (long)LQ*D1, 1.0f,
        nullptr, nullptr, nullptr, nullptr, 0, 0, rsum);

    // ---- output: out = Ctx @ Wo^T + bo  (fp32, fold into M OK, nx=16, ny=32)
    mm_bf16<128, 64, EPI_F32_BIAS><<<dim3((D1/64)*((BB*LQ)/128), 1, 1), 256, 0, stream>>>(
        Ctx, Wobf, out, bo, D1/64, D1, D1, D1, D1, 0, 0, 0, 1.0f,
        nullptr, nullptr, nullptr, nullptr, 0, 0, nullptr);
}

// Round 9
// 275.142 us; speedup vs baseline: 2.8361x; 1.0031x over previous
//
#include <hip/hip_runtime.h>

// Problem dims (fixed)
#define BB   4
#define LQ   1024
#define LK   2048
#define D1   1024
#define D2   1280

typedef unsigned short u16;
typedef __attribute__((ext_vector_type(8))) short   short8;   // 8 bf16 = 4 VGPRs
typedef __attribute__((ext_vector_type(4))) float   floatx4;  // MFMA accum

__device__ __forceinline__ u16 f2bf(float f) {
    unsigned u = __float_as_uint(f);
    unsigned r = (u + 0x7FFFu + ((u >> 16) & 1u)) >> 16;   // RNE
    return (u16)r;
}

// async global->LDS, 16B per lane; LDS dest = wave-uniform base + lane*16
__device__ __forceinline__ void gl_lds16(const void* g, void* l) {
    __builtin_amdgcn_global_load_lds(
        (const __attribute__((address_space(1))) unsigned int*)g,
        (__attribute__((address_space(3))) unsigned int*)l, 16, 0, 0);
}

// ---------------------------------------------------------------------------
// Batched fp32 -> bf16 cast: 6 tensors, ONE launch, 1 quad/thread one-shot.
// R18 grid-stride@3468 measured 51 us vs 44 one-shot (fewer resident loads)
// — reverted. This is the best of FOUR measured variants (1-quad one-shot 44,
// 4-quad 50, paired-16B 53, grid-stride 51). Also zeroes rsum.
// ---------------------------------------------------------------------------
struct CastDesc {
    const float* src[6];
    u16*         dst[6];
    long         end[6];      // cumulative end in QUADS (4 elems)
};

__global__ __launch_bounds__(256) void cast6_kernel(CastDesc d, long total_quads,
                                                    float* __restrict__ rs0)
{
    if (blockIdx.x < 16)
        rs0[blockIdx.x * 256 + threadIdx.x] = 0.f;   // 16*256 = 4096 = BB*LQ

    long gi = (long)blockIdx.x * 256 + threadIdx.x;
    if (gi >= total_quads) return;
    int s = 0;
    while (gi >= d.end[s]) ++s;            // 6 segments, short loop
    const long start = (s == 0) ? 0 : d.end[s - 1];
    const long q = gi - start;
    const float4 v = *(const float4*)(d.src[s] + q * 4);
    ushort4 o;
    o.x = f2bf(v.x); o.y = f2bf(v.y); o.z = f2bf(v.z); o.w = f2bf(v.w);
    *(ushort4*)(d.dst[s] + q * 4) = o;
}

// ---------------------------------------------------------------------------
// bf16 MFMA GEMM, operands in [rows][K] layout (B is N x K, i.e. x @ W^T):
//   C[bz][m][n] = epi( sum_k A[bz][m][k] * B[bz][n][k] )
// BM x BN tile, BK-wide K-steps, 256 threads = 4 waves, 16x16x32 MFMA,
// global_load_lds(16B) staging, XOR-swizzled LDS (conflicts = 0 measured),
// XCD-aware flattened grid. ny % 8 == 0.
//
// R19: BK is now a template param. KV/scores keep BK=64 (measured plateau).
// ctx (K=2048) and out (K=1024) move to BK=128: same tile/grid/swizzle,
// HALF the barrier+drain events per FLOP (ctx 64->32 barriers). LDS 48 KB
// -> still 2 blocks/CU (96 <= 160 KB). Swizzle generalizes: CH=BK/8 chunks
// per row, chunk ^= row&7 -> 16 reading lanes span 32 banks (bank =
// 4*(chunk mod 8)). m132's BK=128 regress was 128^2-tile occupancy loss,
// which does not apply at 128x64.
// Ledger: 8-phase null x2 (R13/R14); ctx/out 128^2 regress (R4, 1 blk/CU);
// mega grid-sync -510 us (R5); fused cast -36 us (R7); grid-stride cast
// -6 us (R8). If BK=128 is null too -> declare plateau with champion file.
// ---------------------------------------------------------------------------
enum { EPI_F32_BIAS, EPI_KV, EPI_EXP, EPI_ROWSCALE };

template <int BM, int BN, int BK, int EPI>
__global__ __launch_bounds__(256, 2) void mm_bf16(
    const u16* __restrict__ A, const u16* __restrict__ B,
    void* __restrict__ C, const float* __restrict__ bias,
    int nx, int Kd, int lda, int ldb, int ldc,
    long sA, long sB, long sC, float scale,
    const u16* __restrict__ A2, const u16* __restrict__ B2,
    void* __restrict__ C2, const float* __restrict__ bias2,
    int ldc2, long sC2, float* __restrict__ rsum)
{
    constexpr bool TALL = (BM == 256);
    constexpr int  NJ   = TALL ? (BN / 16) : (BN / 32);  // j-frags per wave
    constexpr int  CH   = BK / 8;          // 16B chunks per LDS row
    constexpr int  AISS = BM * BK / 2048;  // A staging issues per thread
    constexpr int  NBI  = BN * BK / 2048;  // B staging issues per thread
    constexpr int  QN   = BK / 32;         // K=32 MFMA steps per K-step

    __shared__ u16 As[BM * BK];      // [m][k] swizzled
    __shared__ u16 Bs[BN * BK];      // [n][k] swizzled

    const int u    = blockIdx.x;
    const int rest = u >> 3;
    const int bx   = rest % nx;
    const int by   = (u & 7) + 8 * (rest / nx);

    const int  bz  = blockIdx.z;
    const bool isV = (EPI == EPI_KV) && (bz >= BB);
    const int  b   = isV ? bz - BB : bz;

    const u16* Ab = (isV ? A2 : A) + (long)b * sA + (long)by * BM * lda;
    const u16* Bb = (isV ? B2 : B) + (long)b * sB + (long)bx * BN * ldb;

    const int t    = threadIdx.x;
    const int w    = t >> 6;              // wave 0..3
    const int l    = t & 63;
    const int l16  = l & 15;
    const int quad = l >> 4;
    const int wm   = TALL ? w * 64 : (w >> 1) * 64;   // wave origin in tile
    const int wn   = TALL ? 0      : (w & 1) * (BN / 2);

    floatx4 acc[4][NJ];
    #pragma unroll
    for (int i = 0; i < 4; ++i)
        #pragma unroll
        for (int j = 0; j < NJ; ++j)
            acc[i][j] = (floatx4){0.f, 0.f, 0.f, 0.f};

    for (int k0 = 0; k0 < Kd; k0 += BK) {
        // ---- stage A (BMxBK) and B (BNxBK), XOR-swizzled source
        #pragma unroll
        for (int c = 0; c < AISS; ++c) {
            const int idx = (w * AISS + c) * 64 + l;  // slot
            const int mr  = idx / CH;                 // row 0..BM-1
            const int kq  = (idx % CH) ^ (mr & 7);    // global chunk for slot
            gl_lds16(Ab + (long)mr * lda + k0 + kq * 8, (char*)As + (w * AISS + c) * 1024);
        }
        #pragma unroll
        for (int c = 0; c < NBI; ++c) {
            const int idx = (w * NBI + c) * 64 + l;
            const int mr  = idx / CH;
            const int kq  = (idx % CH) ^ (mr & 7);
            gl_lds16(Bb + (long)mr * ldb + k0 + kq * 8, (char*)Bs + (w * NBI + c) * 1024);
        }
        __syncthreads();

        // ---- QN x K=32 MFMA steps; fragment chunk = (q*4+quad)^(l&7)
        #pragma unroll
        for (int q = 0; q < QN; ++q) {
            const int sc = ((q * 4 + quad) ^ (l & 7)) * 8;   // swizzled elem off
            short8 af[4], bfr[NJ];
            #pragma unroll
            for (int i = 0; i < 4; ++i)
                af[i]  = *(const short8*)(As + (wm + i * 16 + l16) * BK + sc);
            #pragma unroll
            for (int j = 0; j < NJ; ++j)
                bfr[j] = *(const short8*)(Bs + (wn + j * 16 + l16) * BK + sc);
            #pragma unroll
            for (int i = 0; i < 4; ++i)
                #pragma unroll
                for (int j = 0; j < NJ; ++j)
                    acc[i][j] = __builtin_amdgcn_mfma_f32_16x16x32_bf16(
                        af[i], bfr[j], acc[i][j], 0, 0, 0);
        }
        __syncthreads();
    }

    // ---- epilogue: C/D layout col = lane&15, row = quad*4 + reg
    const int mb = by * BM + wm;
    const int nb = bx * BN + wn;

    if (EPI == EPI_F32_BIAS) {
        float* Cp = (float*)C + (long)bz * sC;
        #pragma unroll
        for (int i = 0; i < 4; ++i)
            #pragma unroll
            for (int j = 0; j < NJ; ++j) {
                const int col  = nb + j * 16 + l16;
                const int row0 = mb + i * 16 + quad * 4;
                const float bs = bias[col];
                #pragma unroll
                for (int r = 0; r < 4; ++r)
                    Cp[(long)(row0 + r) * ldc + col] = acc[i][j][r] + bs;
            }
    } else if (EPI == EPI_KV) {
        if (!isV) {        // K-proj: row-major bf16 + bias
            u16* Cp = (u16*)C + (long)b * sC;
            #pragma unroll
            for (int i = 0; i < 4; ++i)
                #pragma unroll
                for (int j = 0; j < NJ; ++j) {
                    const int col  = nb + j * 16 + l16;
                    const int row0 = mb + i * 16 + quad * 4;
                    const float bs = bias[col];
                    #pragma unroll
                    for (int r = 0; r < 4; ++r)
                        Cp[(long)(row0 + r) * ldc + col] = f2bf(acc[i][j][r] + bs);
                }
        } else {           // V-proj: transposed store C2^T[col][row0..+3]
            u16* Cp = (u16*)C2 + (long)b * sC2;
            #pragma unroll
            for (int i = 0; i < 4; ++i)
                #pragma unroll
                for (int j = 0; j < NJ; ++j) {
                    const int col  = nb + j * 16 + l16;
                    const int row0 = mb + i * 16 + quad * 4;
                    const float bs = bias2[col];
                    const floatx4 v = acc[i][j];
                    ushort4 pk;
                    pk.x = f2bf(v[0] + bs); pk.y = f2bf(v[1] + bs);
                    pk.z = f2bf(v[2] + bs); pk.w = f2bf(v[3] + bs);
                    *(ushort4*)(Cp + (long)col * ldc2 + row0) = pk;
                }
        }
    } else if (EPI == EPI_EXP) {
        // E = bf16(exp(acc*scale)); accumulate per-row sums -> atomicAdd
        u16* Cp = (u16*)C + (long)bz * sC;
        float lsum[4][4];
        #pragma unroll
        for (int i = 0; i < 4; ++i)
            #pragma unroll
            for (int r = 0; r < 4; ++r)
                lsum[i][r] = 0.f;
        #pragma unroll
        for (int i = 0; i < 4; ++i)
            #pragma unroll
            for (int j = 0; j < NJ; ++j) {
                const int col  = nb + j * 16 + l16;
                const int row0 = mb + i * 16 + quad * 4;
                #pragma unroll
                for (int r = 0; r < 4; ++r) {
                    const float e = __expf(acc[i][j][r] * scale);
                    Cp[(long)(row0 + r) * ldc + col] = f2bf(e);
                    lsum[i][r] += e;
                }
            }
        // reduce across the 16 l16-lanes of each quad, one atomic per row
        float* rp = rsum + (long)bz * LQ;
        #pragma unroll
        for (int i = 0; i < 4; ++i)
            #pragma unroll
            for (int r = 0; r < 4; ++r) {
                float s = lsum[i][r];
                s += __shfl_xor(s, 1);
                s += __shfl_xor(s, 2);
                s += __shfl_xor(s, 4);
                s += __shfl_xor(s, 8);
                if (l16 == 0)
                    atomicAdd(rp + mb + i * 16 + quad * 4 + r, s);
            }
    } else { // EPI_ROWSCALE: bf16(acc / rowsum[row])
        u16* Cp = (u16*)C + (long)bz * sC;
        const float* rp = rsum + (long)bz * LQ;
        #pragma unroll
        for (int i = 0; i < 4; ++i) {
            const int row0 = mb + i * 16 + quad * 4;
            float inv[4];
            #pragma unroll
            for (int r = 0; r < 4; ++r)
                inv[r] = 1.0f / rp[row0 + r];
            #pragma unroll
            for (int j = 0; j < NJ; ++j) {
                const int col = nb + j * 16 + l16;
                #pragma unroll
                for (int r = 0; r < 4; ++r)
                    Cp[(long)(row0 + r) * ldc + col] = f2bf(acc[i][j][r] * inv[r]);
            }
        }
    }
}

// ---------------------------------------------------------------------------
extern "C" void kernel_launch(void* const* d_in, const int* in_sizes, int n_in,
                              void* d_out, int out_size, void* d_ws, size_t ws_size,
                              hipStream_t stream)
{
    const float* Q  = (const float*)d_in[0];
    const float* K  = (const float*)d_in[1];
    const float* V  = (const float*)d_in[2];
    const float* Wk = (const float*)d_in[3];
    const float* bk = (const float*)d_in[4];
    const float* Wv = (const float*)d_in[5];
    const float* bv = (const float*)d_in[6];
    const float* Wo = (const float*)d_in[7];
    const float* bo = (const float*)d_in[8];
    float* out = (float*)d_out;

    // Workspace layout (max extent 94.4 MB + 16 KB):
    //   Kbf  [0.0, 22.0)M   dead after KV-proj; E aliases its head
    //   Vbf  [22.0, 44.0)M  dead after KV-proj
    //   Qbf  [44.0, 52.4)M  dead after scores
    //   Wkbf/Wvbf/Wobf [52.8, 60.4)M
    //   Kp   [60.8, 77.6)M  dead after scores; Ctx aliases it
    //   VpT  [77.6, 94.4)M
    //   E    [0.0, 16.8)M   bf16 exp-scores (aliases dead Kbf)
    //   rsum [94.4M, +16K)  fp32 per-row exp sums
    char* ws = (char*)d_ws;
    u16*   Kbf  = (u16*)(ws);
    u16*   Vbf  = (u16*)(ws + 22020096);
    u16*   Qbf  = (u16*)(ws + 44040192);
    u16*   Wkbf = (u16*)(ws + 52828160);
    u16*   Wvbf = (u16*)(ws + 55574528);
    u16*   Wobf = (u16*)(ws + 58320896);
    u16*   Kp   = (u16*)(ws + 60817408);
    u16*   VpT  = (u16*)(ws + 77594624);
    u16*   E    = (u16*)(ws);
    float* rsum = (float*)(ws + 94371840);
    u16*   Ctx  = Kp;

    const float inv_sqrt_d = 0.03125f;   // 1/sqrt(1024)

    // ---- one batched cast launch (also zeroes rsum), one-shot grid
    CastDesc cd;
    cd.src[0] = K;  cd.dst[0] = Kbf;
    cd.src[1] = V;  cd.dst[1] = Vbf;
    cd.src[2] = Q;  cd.dst[2] = Qbf;
    cd.src[3] = Wk; cd.dst[3] = Wkbf;
    cd.src[4] = Wv; cd.dst[4] = Wvbf;
    cd.src[5] = Wo; cd.dst[5] = Wobf;
    long acc = 0;
    const long sizes[6] = {(long)BB*LK*D2, (long)BB*LK*D2, (long)BB*LQ*D1,
                           (long)D1*D2, (long)D1*D2, (long)D1*D1};
    for (int i = 0; i < 6; ++i) { acc += sizes[i] / 4; cd.end[i] = acc; }
    cast6_kernel<<<dim3((unsigned)((acc + 255) / 256)), 256, 0, stream>>>(cd, acc, rsum);

    // ---- merged K/V projections, 256x128 tiles, BK=64, z=8 (512 blocks)
    mm_bf16<256, 128, 64, EPI_KV><<<dim3((D1/128)*(LK/256), 1, 2*BB), 256, 0, stream>>>(
        Kbf, Wkbf, Kp, bk, D1/128, D2, D2, D2, D1,
        (long)LK*D2, 0, (long)LK*D1, 1.0f,
        Vbf, Wvbf, VpT, bv, LK, (long)D1*LK, nullptr);

    // ---- fused scores+exp: E[b][q][k] = exp(Q@Kp^T / 32), BK=64 (512 blocks)
    mm_bf16<128, 128, 64, EPI_EXP><<<dim3((LK/128)*(LQ/128), 1, BB), 256, 0, stream>>>(
        Qbf, Kp, E, nullptr, LK/128, D1, D1, D1, LK,
        (long)LQ*D1, (long)LK*D1, (long)LQ*LK, inv_sqrt_d,
        nullptr, nullptr, nullptr, nullptr, 0, 0, rsum);

    // ---- context with fused normalization: Ctx = (E @ VpT^T) / rsum[row]
    // R19: BK=128 — K=2048, barrier count 64 -> 32
    mm_bf16<128, 64, 128, EPI_ROWSCALE><<<dim3((D1/64)*(LQ/128), 1, BB), 256, 0, stream>>>(
        E, VpT, Ctx, nullptr, D1/64, LK, LK, LK, D1,
        (long)LQ*LK, (long)D1*LK, (long)LQ*D1, 1.0f,
        nullptr, nullptr, nullptr, nullptr, 0, 0, rsum);

    // ---- output: out = Ctx @ Wo^T + bo  (R19: BK=128, barriers 32 -> 16)
    mm_bf16<128, 64, 128, EPI_F32_BIAS><<<dim3((D1/64)*((BB*LQ)/128), 1, 1), 256, 0, stream>>>(
        Ctx, Wobf, out, bo, D1/64, D1, D1, D1, D1, 0, 0, 0, 1.0f,
        nullptr, nullptr, nullptr, nullptr, 0, 0, nullptr);
}